// Round 1
// baseline (528.133 us; speedup 1.0000x reference)
//
#include <hip/hip_runtime.h>
#include <math.h>

// Problem constants
#define B_   32
#define T_   128
#define CIN  4096
#define NF   64
#define GOUT 4096
#define NROW 4096   // B_*T_

typedef unsigned short u16;
typedef __attribute__((ext_vector_type(4))) float  f32x4;
typedef __attribute__((ext_vector_type(8))) __bf16 bf16x8;
typedef __attribute__((ext_vector_type(8))) u16    u16x8;

__device__ __forceinline__ u16 f2bf(float f) {   // RNE f32->bf16
  union { float f; unsigned u; } v; v.f = f;
  unsigned r = v.u + 0x7fffu + ((v.u >> 16) & 1u);
  return (u16)(r >> 16);
}

__device__ __forceinline__ void gload_lds16(const void* g, void* l) {
  __builtin_amdgcn_global_load_lds(
      (const __attribute__((address_space(1))) void*)g,
      (__attribute__((address_space(3))) void*)l, 16, 0, 0);
}

// ---------------- 1) wg f32 -> bf16 ----------------
__global__ void k_conv_wg(const float* __restrict__ wg, u16* __restrict__ wgb) {
  size_t i = ((size_t)blockIdx.x * 256 + threadIdx.x) * 8;
  f32x4 a = *(const f32x4*)&wg[i];
  f32x4 b = *(const f32x4*)&wg[i + 4];
  u16x8 o;
  o[0]=f2bf(a[0]); o[1]=f2bf(a[1]); o[2]=f2bf(a[2]); o[3]=f2bf(a[3]);
  o[4]=f2bf(b[0]); o[5]=f2bf(b[1]); o[6]=f2bf(b[2]); o[7]=f2bf(b[3]);
  *(u16x8*)&wgb[i] = o;
}

// ---------------- 2) q/k partial GEMMs (f32, K-split) ----------------
// grid (8 ksplit, 64 rowtiles, 2 which). part layout: [2][8][4096][64] f32
__global__ void k_qk_partial(const float* __restrict__ x1, const float* __restrict__ x2,
                             const float* __restrict__ w1, const float* __restrict__ w2,
                             float* __restrict__ part) {
  const int ks = blockIdx.x, rt = blockIdx.y, which = blockIdx.z;
  const float* __restrict__ X = which ? x2 : x1;
  const float* __restrict__ W = which ? w2 : w1;
  __shared__ float xs[64][132];   // rows of X, padded -> 2-way reads
  __shared__ float wsm[64][129];  // rows of W (n-major), padded
  const int tid = threadIdx.x;
  const int n4 = (tid & 15) * 4;
  const int r4 = (tid >> 4) * 4;
  float acc[4][4] = {};
  for (int kc = 0; kc < 4; ++kc) {
    const int kbase = ks * 512 + kc * 128;
    __syncthreads();   // protect previous-iter reads
    #pragma unroll
    for (int i = 0; i < 8; ++i) {            // stage X: 64 rows x 128 cols
      int f = tid + i * 256; int r = f >> 5, c = (f & 31) * 4;
      f32x4 v = *(const f32x4*)&X[(size_t)(rt * 64 + r) * CIN + kbase + c];
      xs[r][c] = v[0]; xs[r][c+1] = v[1]; xs[r][c+2] = v[2]; xs[r][c+3] = v[3];
    }
    #pragma unroll
    for (int i = 0; i < 8; ++i) {            // stage W: 64 rows x 128 cols
      int f = tid + i * 256; int n = f >> 5, c = (f & 31) * 4;
      f32x4 v = *(const f32x4*)&W[(size_t)n * CIN + kbase + c];
      wsm[n][c] = v[0]; wsm[n][c+1] = v[1]; wsm[n][c+2] = v[2]; wsm[n][c+3] = v[3];
    }
    __syncthreads();
    for (int kk = 0; kk < 128; ++kk) {
      float wv[4], xv[4];
      #pragma unroll
      for (int j = 0; j < 4; ++j) wv[j] = wsm[n4 + j][kk];
      #pragma unroll
      for (int i = 0; i < 4; ++i) xv[i] = xs[r4 + i][kk];
      #pragma unroll
      for (int i = 0; i < 4; ++i)
        #pragma unroll
        for (int j = 0; j < 4; ++j)
          acc[i][j] += xv[i] * wv[j];
    }
  }
  #pragma unroll
  for (int i = 0; i < 4; ++i)
    #pragma unroll
    for (int j = 0; j < 4; ++j)
      part[(((size_t)which * 8 + ks) * NROW + rt * 64 + r4 + i) * 64 + n4 + j] = acc[i][j];
}

// ---------------- 3) reduce partials + bias -> q,k ----------------
__global__ void k_qk_reduce(const float* __restrict__ part,
                            const float* __restrict__ b1, const float* __restrict__ b2,
                            float* __restrict__ q, float* __restrict__ kq) {
  int idx = blockIdx.x * 256 + threadIdx.x;   // 0 .. 524287
  int which = idx >> 18;
  int rn = idx & 262143;
  int n = rn & 63;
  float s = which ? b2[n] : b1[n];
  const float* p = part + (size_t)which * 8 * 262144 + rn;
  #pragma unroll
  for (int i = 0; i < 8; ++i) s += p[(size_t)i * 262144];
  (which ? kq : q)[rn] = s;
}

// ---------------- 4) scores + act + rowsum (one block per batch) ----------------
__global__ void k_scores(const float* __restrict__ q, const float* __restrict__ kbuf,
                         const float* __restrict__ aw,
                         float* __restrict__ act, float* __restrict__ rowsum) {
  __shared__ float qs[128][66], ks2[128][66];
  __shared__ float sc[128][129];
  __shared__ float mx[128], sm[128];
  const int b = blockIdx.x, tid = threadIdx.x;
  #pragma unroll
  for (int i = 0; i < 8; ++i) {               // stage q,k : 128x64 each
    int f = tid + i * 256; int r = f >> 4, c = (f & 15) * 4;
    f32x4 vq = *(const f32x4*)&q[((size_t)b * 128 + r) * 64 + c];
    qs[r][c] = vq[0]; qs[r][c+1] = vq[1]; qs[r][c+2] = vq[2]; qs[r][c+3] = vq[3];
    f32x4 vk = *(const f32x4*)&kbuf[((size_t)b * 128 + r) * 64 + c];
    ks2[r][c] = vk[0]; ks2[r][c+1] = vk[1]; ks2[r][c+2] = vk[2]; ks2[r][c+3] = vk[3];
  }
  __syncthreads();
  const int tx = tid & 15, ty = tid >> 4;
  float a8[8][8] = {};
  for (int c = 0; c < 64; ++c) {
    float qv[8], kv[8];
    #pragma unroll
    for (int i = 0; i < 8; ++i) qv[i] = qs[ty * 8 + i][c];
    #pragma unroll
    for (int j = 0; j < 8; ++j) kv[j] = ks2[tx + j * 16][c];
    #pragma unroll
    for (int i = 0; i < 8; ++i)
      #pragma unroll
      for (int j = 0; j < 8; ++j)
        a8[i][j] += qv[i] * kv[j];
  }
  #pragma unroll
  for (int i = 0; i < 8; ++i)
    #pragma unroll
    for (int j = 0; j < 8; ++j)
      sc[ty * 8 + i][tx + j * 16] = a8[i][j];
  __syncthreads();
  if (tid < 128) {                            // column softmax stats (axis=1 == over t)
    int s = tid; float m = -INFINITY;
    for (int t = 0; t < 128; ++t) m = fmaxf(m, sc[t][s]);
    float ss = 0.f;
    for (int t = 0; t < 128; ++t) ss += __expf(sc[t][s] - m);
    mx[s] = m; sm[s] = ss;
  }
  __syncthreads();
  const float w0 = aw[0], w1a = aw[1], w2a = aw[2];
  #pragma unroll
  for (int i = 0; i < 8; ++i)
    #pragma unroll
    for (int j = 0; j < 8; ++j) {
      int t = ty * 8 + i, s = tx + j * 16;
      float v = sc[t][s];
      float av = w0 * fmaxf(v, 0.f)
               + w1a * (1.f / (1.f + __expf(-v)))
               + w2a * (__expf(v - mx[s]) / sm[s]);
      act[((size_t)b * 128 + t) * 128 + s] = av;
      sc[t][s] = av;                          // own slot; re-read after barrier
    }
  __syncthreads();
  if (tid < 128) {
    int t = tid; float s_ = 0.f;
    for (int s = 0; s < 128; ++s) s_ += sc[t][s];
    rowsum[b * 128 + t] = s_;
  }
}

// ---------------- 5) y = act @ x1, written as bf16 ----------------
// grid (32 col-chunks, 32 batches)
__global__ void k_y(const float* __restrict__ act, const float* __restrict__ x1,
                    u16* __restrict__ yb) {
  __shared__ float actS[128][128];
  __shared__ float xS[128][128];
  const int b = blockIdx.y, c0 = blockIdx.x * 128, tid = threadIdx.x;
  #pragma unroll
  for (int i = 0; i < 16; ++i) {
    int f = tid + i * 256; int r = f >> 5, c = (f & 31) * 4;
    *(f32x4*)&actS[r][c] = *(const f32x4*)&act[((size_t)b * 128 + r) * 128 + c];
    *(f32x4*)&xS[r][c]   = *(const f32x4*)&x1[((size_t)b * 128 + r) * CIN + c0 + c];
  }
  __syncthreads();
  const int c4 = (tid & 31) * 4, tq = tid >> 5;   // 8 t-groups of 16
  f32x4 acc[16];
  #pragma unroll
  for (int i = 0; i < 16; ++i) acc[i] = (f32x4){0.f, 0.f, 0.f, 0.f};
  for (int s = 0; s < 128; ++s) {
    f32x4 xv = *(const f32x4*)&xS[s][c4];
    #pragma unroll
    for (int i = 0; i < 16; ++i) {
      float av = actS[tq * 16 + i][s];   // wave-uniform broadcast
      acc[i] += xv * av;
    }
  }
  #pragma unroll
  for (int i = 0; i < 16; ++i) {
    int t = tq * 16 + i;
    u16 o0 = f2bf(acc[i][0]), o1 = f2bf(acc[i][1]), o2 = f2bf(acc[i][2]), o3 = f2bf(acc[i][3]);
    u16* p = &yb[((size_t)b * 128 + t) * CIN + c0 + c4];
    p[0] = o0; p[1] = o1; p[2] = o2; p[3] = o3;
  }
}

// ---------------- 6) out = y(bf16) @ wg^T(bf16) + rowsum ⊗ bg ----------------
// 128x128 tile, BK=64, 4 waves (2x2), 4x4 frags of mfma_f32_16x16x32_bf16.
// global_load_lds width=16; XOR chunk swizzle (chunk ^= row&7) applied on the
// GLOBAL SOURCE (LDS dest linear, per m104/m173) and on the ds_read side.
#define BM 128
#define BN 128
#define BK 64
__global__ __launch_bounds__(256) void k_gemm(
    const u16* __restrict__ A, const u16* __restrict__ Bw,
    const float* __restrict__ rowsum, const float* __restrict__ bg,
    float* __restrict__ C) {
  __shared__ __align__(16) u16 As[BM * BK];   // 16 KB
  __shared__ __align__(16) u16 Bs[BN * BK];   // 16 KB
  const int tid = threadIdx.x;
  const int wave = tid >> 6, lane = tid & 63;
  const int row0 = blockIdx.y * BM, col0 = blockIdx.x * BN;
  const int wm = wave >> 1, wn = wave & 1;
  const int fr = lane & 15, fk = lane >> 4;

  // staging source (per-thread): row = i*32 + (tid>>3), source chunk pre-swizzled
  const int srow = tid >> 3;
  const int schunk = (tid & 7) ^ (srow & 7);
  const u16* Abase = A + (size_t)(row0 + srow) * CIN + schunk * 8;
  const u16* Bbase = Bw + (size_t)(col0 + srow) * CIN + schunk * 8;

  f32x4 acc[4][4];
  #pragma unroll
  for (int a = 0; a < 4; ++a)
    #pragma unroll
    for (int b = 0; b < 4; ++b) acc[a][b] = (f32x4){0.f, 0.f, 0.f, 0.f};

  for (int kt = 0; kt < CIN; kt += BK) {
    #pragma unroll
    for (int i = 0; i < 4; ++i) {   // 4 KB per round, wave-uniform LDS base
      gload_lds16(Abase + (size_t)i * 32 * CIN + kt, (char*)As + i * 4096 + wave * 1024);
      gload_lds16(Bbase + (size_t)i * 32 * CIN + kt, (char*)Bs + i * 4096 + wave * 1024);
    }
    __syncthreads();   // drains vmcnt before barrier (compiler-emitted)
    #pragma unroll
    for (int ks = 0; ks < 2; ++ks) {
      bf16x8 af[4], bf[4];
      #pragma unroll
      for (int a = 0; a < 4; ++a) {
        int r = wm * 64 + a * 16 + fr;
        int ch = (ks * 4 + fk) ^ (r & 7);
        af[a] = *(const bf16x8*)((const char*)As + r * 128 + ch * 16);
      }
      #pragma unroll
      for (int b = 0; b < 4; ++b) {
        int r = wn * 64 + b * 16 + fr;
        int ch = (ks * 4 + fk) ^ (r & 7);
        bf[b] = *(const bf16x8*)((const char*)Bs + r * 128 + ch * 16);
      }
      #pragma unroll
      for (int a = 0; a < 4; ++a)
        #pragma unroll
        for (int b = 0; b < 4; ++b)
          acc[a][b] = __builtin_amdgcn_mfma_f32_16x16x32_bf16(af[a], bf[b], acc[a][b], 0, 0, 0);
    }
    __syncthreads();
  }

  // epilogue: C[m][n], m=(lane>>4)*4+j, n=lane&15 (m89-verified layout)
  float bgv[4];
  #pragma unroll
  for (int b = 0; b < 4; ++b) bgv[b] = bg[col0 + wn * 64 + b * 16 + fr];
  #pragma unroll
  for (int a = 0; a < 4; ++a)
    #pragma unroll
    for (int j = 0; j < 4; ++j) {
      int r = row0 + wm * 64 + a * 16 + fk * 4 + j;
      float rs = rowsum[r];
      #pragma unroll
      for (int b = 0; b < 4; ++b) {
        int c = col0 + wn * 64 + b * 16 + fr;
        C[(size_t)r * GOUT + c] = acc[a][b][j] + rs * bgv[b];
      }
    }
}

extern "C" void kernel_launch(void* const* d_in, const int* in_sizes, int n_in,
                              void* d_out, int out_size, void* d_ws, size_t ws_size,
                              hipStream_t stream) {
  const float* x1 = (const float*)d_in[0];
  const float* x2 = (const float*)d_in[1];
  const float* aw = (const float*)d_in[2];
  const float* w1 = (const float*)d_in[3];
  const float* b1 = (const float*)d_in[4];
  const float* w2 = (const float*)d_in[5];
  const float* b2 = (const float*)d_in[6];
  const float* wg = (const float*)d_in[7];
  const float* bg = (const float*)d_in[8];
  float* out = (float*)d_out;
  char* ws = (char*)d_ws;

  // workspace map (~68 MiB total; partials alias the yb region, consumed before k_y writes)
  u16*   wgb  = (u16*)(ws);                       // 32 MiB
  u16*   yb   = (u16*)(ws + 33554432);            // 32 MiB
  float* part = (float*)(ws + 33554432);          // 16 MiB (aliases yb; dead before k_y)
  float* q    = (float*)(ws + 67108864);          // 1 MiB
  float* kq   = (float*)(ws + 68157440);          // 1 MiB
  float* act  = (float*)(ws + 69206016);          // 2 MiB
  float* rsum = (float*)(ws + 71303168);          // 16 KiB

  hipLaunchKernelGGL(k_conv_wg,   dim3(8192),      dim3(256), 0, stream, wg, wgb);
  hipLaunchKernelGGL(k_qk_partial,dim3(8, 64, 2),  dim3(256), 0, stream, x1, x2, w1, w2, part);
  hipLaunchKernelGGL(k_qk_reduce, dim3(2048),      dim3(256), 0, stream, part, b1, b2, q, kq);
  hipLaunchKernelGGL(k_scores,    dim3(32),        dim3(256), 0, stream, q, kq, aw, act, rsum);
  hipLaunchKernelGGL(k_y,         dim3(32, 32),    dim3(256), 0, stream, act, x1, yb);
  hipLaunchKernelGGL(k_gemm,      dim3(32, 32),    dim3(256), 0, stream, yb, wgb, rsum, bg, out);
}

// Round 2
// 517.514 us; speedup vs baseline: 1.0205x; 1.0205x over previous
//
#include <hip/hip_runtime.h>
#include <math.h>

// Problem constants
#define B_   32
#define T_   128
#define CIN  4096
#define NF   64
#define GOUT 4096

typedef unsigned short u16;
typedef __attribute__((ext_vector_type(4))) float  f32x4;
typedef __attribute__((ext_vector_type(8))) __bf16 bf16x8;
typedef __attribute__((ext_vector_type(8))) u16    u16x8;

__device__ __forceinline__ u16 f2bf(float f) {   // RNE f32->bf16
  union { float f; unsigned u; } v; v.f = f;
  unsigned r = v.u + 0x7fffu + ((v.u >> 16) & 1u);
  return (u16)(r >> 16);
}

__device__ __forceinline__ void gload_lds16(const void* g, void* l) {
  __builtin_amdgcn_global_load_lds(
      (const __attribute__((address_space(1))) void*)g,
      (__attribute__((address_space(3))) void*)l, 16, 0, 0);
}

// ---------------- 1) wg f32 -> bf16 ----------------
__global__ void k_conv_wg(const float* __restrict__ wg, u16* __restrict__ wgb) {
  size_t i = ((size_t)blockIdx.x * 256 + threadIdx.x) * 8;
  f32x4 a = *(const f32x4*)&wg[i];
  f32x4 b = *(const f32x4*)&wg[i + 4];
  u16x8 o;
  o[0]=f2bf(a[0]); o[1]=f2bf(a[1]); o[2]=f2bf(a[2]); o[3]=f2bf(a[3]);
  o[4]=f2bf(b[0]); o[5]=f2bf(b[1]); o[6]=f2bf(b[2]); o[7]=f2bf(b[3]);
  *(u16x8*)&wgb[i] = o;
}

// ---------------- 2) x1 -> x1tb : per-batch transpose + bf16 ----------------
// x1tb layout: [B][CIN][T] bf16. Block = (c-tile 128, batch). LDS f32 transpose.
__global__ __launch_bounds__(256) void k_x1t(const float* __restrict__ x1,
                                             u16* __restrict__ x1tb) {
  __shared__ float tile[128][132];   // pad 4 -> 2-way-free column reads
  const int b = blockIdx.y, c0 = blockIdx.x * 128, tid = threadIdx.x;
  #pragma unroll
  for (int i = 0; i < 16; ++i) {
    int f = tid + i * 256; int s = f >> 5, c4 = (f & 31) * 4;
    f32x4 v = *(const f32x4*)&x1[((size_t)b * 128 + s) * CIN + c0 + c4];
    tile[s][c4] = v[0]; tile[s][c4+1] = v[1]; tile[s][c4+2] = v[2]; tile[s][c4+3] = v[3];
  }
  __syncthreads();
  const int c = tid >> 1, sh = (tid & 1) * 64;
  #pragma unroll
  for (int i = 0; i < 8; ++i) {
    u16x8 o;
    #pragma unroll
    for (int j = 0; j < 8; ++j) o[j] = f2bf(tile[sh + i * 8 + j][c]);
    *(u16x8*)&x1tb[((size_t)b * CIN + c0 + c) * 128 + sh + i * 8] = o;
  }
}

// ---------------- 3) q/k via MFMA, inline f32->bf16 staging ----------------
// grid (32 row-tiles, 2 which), 512 threads (8 waves, 16 rows each).
__global__ __launch_bounds__(512) void k_qk(
    const float* __restrict__ x1, const float* __restrict__ x2,
    const float* __restrict__ w1, const float* __restrict__ w2,
    const float* __restrict__ b1v, const float* __restrict__ b2v,
    float* __restrict__ q, float* __restrict__ kq) {
  const int rt = blockIdx.x, which = blockIdx.y;
  const float* __restrict__ X   = which ? x2  : x1;
  const float* __restrict__ W   = which ? w2  : w1;
  const float* __restrict__ bia = which ? b2v : b1v;
  float* __restrict__ outp      = which ? kq  : q;
  __shared__ __align__(16) u16 Xs[128 * 64];   // 16KB, XOR-swizzled chunks
  __shared__ __align__(16) u16 Ws[64 * 64];    // 8KB
  const int tid = threadIdx.x;
  const int wave = tid >> 6, lane = tid & 63;
  const int fr = lane & 15, fk = lane >> 4;
  f32x4 acc[4];
  #pragma unroll
  for (int b = 0; b < 4; ++b) acc[b] = (f32x4){0.f, 0.f, 0.f, 0.f};

  for (int kt = 0; kt < CIN; kt += 64) {
    __syncthreads();
    #pragma unroll
    for (int i = 0; i < 2; ++i) {   // X: 1024 chunks, 2/thread
      int ci = tid + i * 512; int r = ci >> 3, c8 = ci & 7;
      const float* s = &X[((size_t)rt * 128 + r) * CIN + kt + c8 * 8];
      f32x4 va = *(const f32x4*)s, vb = *(const f32x4*)(s + 4);
      bf16x8 o;
      o[0]=(__bf16)va[0]; o[1]=(__bf16)va[1]; o[2]=(__bf16)va[2]; o[3]=(__bf16)va[3];
      o[4]=(__bf16)vb[0]; o[5]=(__bf16)vb[1]; o[6]=(__bf16)vb[2]; o[7]=(__bf16)vb[3];
      *(bf16x8*)((char*)Xs + r * 128 + ((c8 ^ (r & 7)) * 16)) = o;
    }
    {                                // W: 512 chunks, 1/thread
      int r = tid >> 3, c8 = tid & 7;
      const float* s = &W[(size_t)r * CIN + kt + c8 * 8];
      f32x4 va = *(const f32x4*)s, vb = *(const f32x4*)(s + 4);
      bf16x8 o;
      o[0]=(__bf16)va[0]; o[1]=(__bf16)va[1]; o[2]=(__bf16)va[2]; o[3]=(__bf16)va[3];
      o[4]=(__bf16)vb[0]; o[5]=(__bf16)vb[1]; o[6]=(__bf16)vb[2]; o[7]=(__bf16)vb[3];
      *(bf16x8*)((char*)Ws + r * 128 + ((c8 ^ (r & 7)) * 16)) = o;
    }
    __syncthreads();
    #pragma unroll
    for (int ks = 0; ks < 2; ++ks) {
      int ra = wave * 16 + fr;
      bf16x8 af = *(const bf16x8*)((const char*)Xs + ra * 128 + (((ks * 4 + fk) ^ (ra & 7)) * 16));
      #pragma unroll
      for (int b = 0; b < 4; ++b) {
        int rb = b * 16 + fr;
        bf16x8 bf = *(const bf16x8*)((const char*)Ws + rb * 128 + (((ks * 4 + fk) ^ (rb & 7)) * 16));
        acc[b] = __builtin_amdgcn_mfma_f32_16x16x32_bf16(af, bf, acc[b], 0, 0, 0);
      }
    }
  }
  #pragma unroll
  for (int b = 0; b < 4; ++b) {
    float bv = bia[b * 16 + fr];
    #pragma unroll
    for (int j = 0; j < 4; ++j) {
      int row = rt * 128 + wave * 16 + fk * 4 + j;
      outp[(size_t)row * 64 + b * 16 + fr] = acc[b][j] + bv;
    }
  }
}

// ---------------- 4) scores + act(bf16) + rowsum (one block per batch) ----------------
__global__ void k_scores(const float* __restrict__ q, const float* __restrict__ kbuf,
                         const float* __restrict__ aw,
                         u16* __restrict__ actb, float* __restrict__ rowsum) {
  __shared__ float qs[128][66], ks2[128][66];
  __shared__ float sc[128][129];
  __shared__ float mx[128], sm[128];
  const int b = blockIdx.x, tid = threadIdx.x;
  #pragma unroll
  for (int i = 0; i < 8; ++i) {               // stage q,k : 128x64 each
    int f = tid + i * 256; int r = f >> 4, c = (f & 15) * 4;
    f32x4 vq = *(const f32x4*)&q[((size_t)b * 128 + r) * 64 + c];
    qs[r][c] = vq[0]; qs[r][c+1] = vq[1]; qs[r][c+2] = vq[2]; qs[r][c+3] = vq[3];
    f32x4 vk = *(const f32x4*)&kbuf[((size_t)b * 128 + r) * 64 + c];
    ks2[r][c] = vk[0]; ks2[r][c+1] = vk[1]; ks2[r][c+2] = vk[2]; ks2[r][c+3] = vk[3];
  }
  __syncthreads();
  const int tx = tid & 15, ty = tid >> 4;
  float a8[8][8] = {};
  for (int c = 0; c < 64; ++c) {
    float qv[8], kv[8];
    #pragma unroll
    for (int i = 0; i < 8; ++i) qv[i] = qs[ty * 8 + i][c];
    #pragma unroll
    for (int j = 0; j < 8; ++j) kv[j] = ks2[tx + j * 16][c];
    #pragma unroll
    for (int i = 0; i < 8; ++i)
      #pragma unroll
      for (int j = 0; j < 8; ++j)
        a8[i][j] += qv[i] * kv[j];
  }
  #pragma unroll
  for (int i = 0; i < 8; ++i)
    #pragma unroll
    for (int j = 0; j < 8; ++j)
      sc[ty * 8 + i][tx + j * 16] = a8[i][j];
  __syncthreads();
  if (tid < 128) {                            // column softmax stats (axis=1 == over t)
    int s = tid; float m = -INFINITY;
    for (int t = 0; t < 128; ++t) m = fmaxf(m, sc[t][s]);
    float ss = 0.f;
    for (int t = 0; t < 128; ++t) ss += __expf(sc[t][s] - m);
    mx[s] = m; sm[s] = ss;
  }
  __syncthreads();
  const float w0 = aw[0], w1a = aw[1], w2a = aw[2];
  #pragma unroll
  for (int i = 0; i < 8; ++i)
    #pragma unroll
    for (int j = 0; j < 8; ++j) {
      int t = ty * 8 + i, s = tx + j * 16;
      float v = sc[t][s];
      float av = w0 * fmaxf(v, 0.f)
               + w1a * (1.f / (1.f + __expf(-v)))
               + w2a * (__expf(v - mx[s]) / sm[s]);
      actb[((size_t)b * 128 + t) * 128 + s] = f2bf(av);
      sc[t][s] = av;                          // own slot; re-read after barrier
    }
  __syncthreads();
  if (tid < 128) {
    int t = tid; float s_ = 0.f;
    for (int s = 0; s < 128; ++s) s_ += sc[t][s];
    rowsum[b * 128 + t] = s_;
  }
}

// ---------------- 5) y = act(bf16) @ x1tb^T via MFMA ----------------
// grid (32 col-blocks, 32 batches), 256 threads (4 waves 2x2), K=128 single shot.
__global__ __launch_bounds__(256) void k_y(const u16* __restrict__ actb,
                                           const u16* __restrict__ x1tb,
                                           u16* __restrict__ yb) {
  __shared__ __align__(16) u16 Ab[128 * 128];  // 32KB, 16-chunk rows, XOR(r&15)
  __shared__ __align__(16) u16 Bs[128 * 128];  // 32KB
  const int bb = blockIdx.y, c0 = blockIdx.x * 128, tid = threadIdx.x;
  const int wave = tid >> 6, lane = tid & 63;
  const int wm = wave >> 1, wn = wave & 1;
  const int fr = lane & 15, fk = lane >> 4;
  #pragma unroll
  for (int i = 0; i < 8; ++i) {
    int ci = tid + i * 256; int r = ci >> 4, c16 = ci & 15;
    u16x8 va = *(const u16x8*)&actb[((size_t)bb * 128 + r) * 128 + c16 * 8];
    *(u16x8*)((char*)Ab + r * 256 + ((c16 ^ (r & 15)) * 16)) = va;
    u16x8 vb = *(const u16x8*)&x1tb[((size_t)bb * CIN + c0 + r) * 128 + c16 * 8];
    *(u16x8*)((char*)Bs + r * 256 + ((c16 ^ (r & 15)) * 16)) = vb;
  }
  __syncthreads();
  f32x4 acc[4][4];
  #pragma unroll
  for (int a = 0; a < 4; ++a)
    #pragma unroll
    for (int b = 0; b < 4; ++b) acc[a][b] = (f32x4){0.f, 0.f, 0.f, 0.f};
  #pragma unroll
  for (int ks = 0; ks < 4; ++ks) {
    bf16x8 af[4], bf[4];
    #pragma unroll
    for (int a = 0; a < 4; ++a) {
      int ra = wm * 64 + a * 16 + fr;
      af[a] = *(const bf16x8*)((const char*)Ab + ra * 256 + (((ks * 4 + fk) ^ (ra & 15)) * 16));
    }
    #pragma unroll
    for (int b = 0; b < 4; ++b) {
      int rb = wn * 64 + b * 16 + fr;
      bf[b] = *(const bf16x8*)((const char*)Bs + rb * 256 + (((ks * 4 + fk) ^ (rb & 15)) * 16));
    }
    #pragma unroll
    for (int a = 0; a < 4; ++a)
      #pragma unroll
      for (int b = 0; b < 4; ++b)
        acc[a][b] = __builtin_amdgcn_mfma_f32_16x16x32_bf16(af[a], bf[b], acc[a][b], 0, 0, 0);
  }
  #pragma unroll
  for (int a = 0; a < 4; ++a)
    #pragma unroll
    for (int j = 0; j < 4; ++j) {
      int t = wm * 64 + a * 16 + fk * 4 + j;
      #pragma unroll
      for (int b = 0; b < 4; ++b) {
        int c = c0 + wn * 64 + b * 16 + fr;
        yb[((size_t)bb * 128 + t) * CIN + c] = f2bf(acc[a][b][j]);
      }
    }
}

// ---------------- 6) out = y(bf16) @ wg^T(bf16) + rowsum ⊗ bg  (unchanged) ----------------
#define BM 128
#define BN 128
#define BK 64
__global__ __launch_bounds__(256) void k_gemm(
    const u16* __restrict__ A, const u16* __restrict__ Bw,
    const float* __restrict__ rowsum, const float* __restrict__ bg,
    float* __restrict__ C) {
  __shared__ __align__(16) u16 As[BM * BK];   // 16 KB
  __shared__ __align__(16) u16 Bs[BN * BK];   // 16 KB
  const int tid = threadIdx.x;
  const int wave = tid >> 6, lane = tid & 63;
  const int row0 = blockIdx.y * BM, col0 = blockIdx.x * BN;
  const int wm = wave >> 1, wn = wave & 1;
  const int fr = lane & 15, fk = lane >> 4;

  const int srow = tid >> 3;
  const int schunk = (tid & 7) ^ (srow & 7);
  const u16* Abase = A + (size_t)(row0 + srow) * CIN + schunk * 8;
  const u16* Bbase = Bw + (size_t)(col0 + srow) * CIN + schunk * 8;

  f32x4 acc[4][4];
  #pragma unroll
  for (int a = 0; a < 4; ++a)
    #pragma unroll
    for (int b = 0; b < 4; ++b) acc[a][b] = (f32x4){0.f, 0.f, 0.f, 0.f};

  for (int kt = 0; kt < CIN; kt += BK) {
    #pragma unroll
    for (int i = 0; i < 4; ++i) {
      gload_lds16(Abase + (size_t)i * 32 * CIN + kt, (char*)As + i * 4096 + wave * 1024);
      gload_lds16(Bbase + (size_t)i * 32 * CIN + kt, (char*)Bs + i * 4096 + wave * 1024);
    }
    __syncthreads();
    #pragma unroll
    for (int ks = 0; ks < 2; ++ks) {
      bf16x8 af[4], bf[4];
      #pragma unroll
      for (int a = 0; a < 4; ++a) {
        int r = wm * 64 + a * 16 + fr;
        int ch = (ks * 4 + fk) ^ (r & 7);
        af[a] = *(const bf16x8*)((const char*)As + r * 128 + ch * 16);
      }
      #pragma unroll
      for (int b = 0; b < 4; ++b) {
        int r = wn * 64 + b * 16 + fr;
        int ch = (ks * 4 + fk) ^ (r & 7);
        bf[b] = *(const bf16x8*)((const char*)Bs + r * 128 + ch * 16);
      }
      #pragma unroll
      for (int a = 0; a < 4; ++a)
        #pragma unroll
        for (int b = 0; b < 4; ++b)
          acc[a][b] = __builtin_amdgcn_mfma_f32_16x16x32_bf16(af[a], bf[b], acc[a][b], 0, 0, 0);
    }
    __syncthreads();
  }

  float bgv[4];
  #pragma unroll
  for (int b = 0; b < 4; ++b) bgv[b] = bg[col0 + wn * 64 + b * 16 + fr];
  #pragma unroll
  for (int a = 0; a < 4; ++a)
    #pragma unroll
    for (int j = 0; j < 4; ++j) {
      int r = row0 + wm * 64 + a * 16 + fk * 4 + j;
      float rs = rowsum[r];
      #pragma unroll
      for (int b = 0; b < 4; ++b) {
        int c = col0 + wn * 64 + b * 16 + fr;
        C[(size_t)r * GOUT + c] = acc[a][b][j] + rs * bgv[b];
      }
    }
}

extern "C" void kernel_launch(void* const* d_in, const int* in_sizes, int n_in,
                              void* d_out, int out_size, void* d_ws, size_t ws_size,
                              hipStream_t stream) {
  const float* x1 = (const float*)d_in[0];
  const float* x2 = (const float*)d_in[1];
  const float* aw = (const float*)d_in[2];
  const float* w1 = (const float*)d_in[3];
  const float* b1 = (const float*)d_in[4];
  const float* w2 = (const float*)d_in[5];
  const float* b2 = (const float*)d_in[6];
  const float* wg = (const float*)d_in[7];
  const float* bg = (const float*)d_in[8];
  float* out = (float*)d_out;
  char* ws = (char*)d_ws;

  // workspace map (100 MB total)
  float* q    = (float*)(ws);                      // 1 MiB
  float* kq   = (float*)(ws + 1048576);            // 1 MiB
  u16*   actb = (u16*)(ws + 2097152);              // 1 MiB
  float* rsum = (float*)(ws + 3145728);            // 16 KiB
  u16*   wgb  = (u16*)(ws + 4194304);              // 32 MiB
  u16*   x1tb = (u16*)(ws + 37748736);             // 32 MiB
  u16*   yb   = (u16*)(ws + 71303168);             // 32 MiB -> end 100 MiB

  hipLaunchKernelGGL(k_conv_wg, dim3(8192),    dim3(256), 0, stream, wg, wgb);
  hipLaunchKernelGGL(k_x1t,     dim3(32, 32),  dim3(256), 0, stream, x1, x1tb);
  hipLaunchKernelGGL(k_qk,      dim3(32, 2),   dim3(512), 0, stream,
                     x1, x2, w1, w2, b1, b2, q, kq);
  hipLaunchKernelGGL(k_scores,  dim3(32),      dim3(256), 0, stream, q, kq, aw, actb, rsum);
  hipLaunchKernelGGL(k_y,       dim3(32, 32),  dim3(256), 0, stream, actb, x1tb, yb);
  hipLaunchKernelGGL(k_gemm,    dim3(32, 32),  dim3(256), 0, stream, yb, wgb, rsum, bg, out);
}

// Round 3
// 449.677 us; speedup vs baseline: 1.1745x; 1.1509x over previous
//
#include <hip/hip_runtime.h>
#include <math.h>

// Problem constants
#define B_   32
#define T_   128
#define CIN  4096
#define NF   64
#define GOUT 4096

typedef unsigned short u16;
typedef __attribute__((ext_vector_type(4))) float  f32x4;
typedef __attribute__((ext_vector_type(8))) __bf16 bf16x8;
typedef __attribute__((ext_vector_type(8))) u16    u16x8;

__device__ __forceinline__ u16 f2bf(float f) {   // RNE f32->bf16
  union { float f; unsigned u; } v; v.f = f;
  unsigned r = v.u + 0x7fffu + ((v.u >> 16) & 1u);
  return (u16)(r >> 16);
}

__device__ __forceinline__ void gload_lds16(const void* g, void* l) {
  __builtin_amdgcn_global_load_lds(
      (const __attribute__((address_space(1))) void*)g,
      (__attribute__((address_space(3))) void*)l, 16, 0, 0);
}

// ---------------- 1) wg f32 -> bf16 ----------------
__global__ void k_conv_wg(const float* __restrict__ wg, u16* __restrict__ wgb) {
  size_t i = ((size_t)blockIdx.x * 256 + threadIdx.x) * 8;
  f32x4 a = *(const f32x4*)&wg[i];
  f32x4 b = *(const f32x4*)&wg[i + 4];
  u16x8 o;
  o[0]=f2bf(a[0]); o[1]=f2bf(a[1]); o[2]=f2bf(a[2]); o[3]=f2bf(a[3]);
  o[4]=f2bf(b[0]); o[5]=f2bf(b[1]); o[6]=f2bf(b[2]); o[7]=f2bf(b[3]);
  *(u16x8*)&wgb[i] = o;
}

// ---------------- 2) x1 -> x1tb : per-batch transpose + bf16 ----------------
__global__ __launch_bounds__(256) void k_x1t(const float* __restrict__ x1,
                                             u16* __restrict__ x1tb) {
  __shared__ float tile[128][132];
  const int b = blockIdx.y, c0 = blockIdx.x * 128, tid = threadIdx.x;
  #pragma unroll
  for (int i = 0; i < 16; ++i) {
    int f = tid + i * 256; int s = f >> 5, c4 = (f & 31) * 4;
    f32x4 v = *(const f32x4*)&x1[((size_t)b * 128 + s) * CIN + c0 + c4];
    tile[s][c4] = v[0]; tile[s][c4+1] = v[1]; tile[s][c4+2] = v[2]; tile[s][c4+3] = v[3];
  }
  __syncthreads();
  const int c = tid >> 1, sh = (tid & 1) * 64;
  #pragma unroll
  for (int i = 0; i < 8; ++i) {
    u16x8 o;
    #pragma unroll
    for (int j = 0; j < 8; ++j) o[j] = f2bf(tile[sh + i * 8 + j][c]);
    *(u16x8*)&x1tb[((size_t)b * CIN + c0 + c) * 128 + sh + i * 8] = o;
  }
}

// ---------------- 3a) q/k partials via MFMA, K-split x8 ----------------
// grid (32 rt, 8 ksp, 2 which), 256 threads (4 waves; wave owns 32 rows).
// part layout: [2][8][4096][64] f32 (deterministic partials, no atomics)
__global__ __launch_bounds__(256) void k_qk_partial(
    const float* __restrict__ x1, const float* __restrict__ x2,
    const float* __restrict__ w1, const float* __restrict__ w2,
    float* __restrict__ part) {
  const int rt = blockIdx.x, ksp = blockIdx.y, which = blockIdx.z;
  const float* __restrict__ X = which ? x2 : x1;
  const float* __restrict__ W = which ? w2 : w1;
  __shared__ __align__(16) u16 Xs[128 * 64];   // 16KB, XOR-swizzled chunks
  __shared__ __align__(16) u16 Ws[64 * 64];    // 8KB
  const int tid = threadIdx.x;
  const int wave = tid >> 6, lane = tid & 63;
  const int fr = lane & 15, fk = lane >> 4;
  f32x4 acc[2][4];
  #pragma unroll
  for (int a = 0; a < 2; ++a)
    #pragma unroll
    for (int b = 0; b < 4; ++b) acc[a][b] = (f32x4){0.f, 0.f, 0.f, 0.f};

  for (int step = 0; step < 8; ++step) {
    const int kbase = ksp * 512 + step * 64;
    __syncthreads();   // protect previous-iter LDS reads
    #pragma unroll
    for (int i = 0; i < 4; ++i) {   // X: 1024 chunks of 8 f32, 4/thread
      int ci = tid + i * 256; int r = ci >> 3, c8 = ci & 7;
      const float* s = &X[((size_t)rt * 128 + r) * CIN + kbase + c8 * 8];
      f32x4 va = *(const f32x4*)s, vb = *(const f32x4*)(s + 4);
      bf16x8 o;
      o[0]=(__bf16)va[0]; o[1]=(__bf16)va[1]; o[2]=(__bf16)va[2]; o[3]=(__bf16)va[3];
      o[4]=(__bf16)vb[0]; o[5]=(__bf16)vb[1]; o[6]=(__bf16)vb[2]; o[7]=(__bf16)vb[3];
      *(bf16x8*)((char*)Xs + r * 128 + ((c8 ^ (r & 7)) * 16)) = o;
    }
    #pragma unroll
    for (int i = 0; i < 2; ++i) {   // W: 512 chunks, 2/thread
      int ci = tid + i * 256; int r = ci >> 3, c8 = ci & 7;
      const float* s = &W[(size_t)r * CIN + kbase + c8 * 8];
      f32x4 va = *(const f32x4*)s, vb = *(const f32x4*)(s + 4);
      bf16x8 o;
      o[0]=(__bf16)va[0]; o[1]=(__bf16)va[1]; o[2]=(__bf16)va[2]; o[3]=(__bf16)va[3];
      o[4]=(__bf16)vb[0]; o[5]=(__bf16)vb[1]; o[6]=(__bf16)vb[2]; o[7]=(__bf16)vb[3];
      *(bf16x8*)((char*)Ws + r * 128 + ((c8 ^ (r & 7)) * 16)) = o;
    }
    __syncthreads();
    #pragma unroll
    for (int ks = 0; ks < 2; ++ks) {
      bf16x8 af[2], bf[4];
      #pragma unroll
      for (int a = 0; a < 2; ++a) {
        int ra = wave * 32 + a * 16 + fr;
        af[a] = *(const bf16x8*)((const char*)Xs + ra * 128 + (((ks * 4 + fk) ^ (ra & 7)) * 16));
      }
      #pragma unroll
      for (int b = 0; b < 4; ++b) {
        int rb = b * 16 + fr;
        bf[b] = *(const bf16x8*)((const char*)Ws + rb * 128 + (((ks * 4 + fk) ^ (rb & 7)) * 16));
      }
      #pragma unroll
      for (int a = 0; a < 2; ++a)
        #pragma unroll
        for (int b = 0; b < 4; ++b)
          acc[a][b] = __builtin_amdgcn_mfma_f32_16x16x32_bf16(af[a], bf[b], acc[a][b], 0, 0, 0);
    }
  }
  float* dst = part + ((size_t)(which * 8 + ksp)) * 262144;
  #pragma unroll
  for (int a = 0; a < 2; ++a)
    #pragma unroll
    for (int j = 0; j < 4; ++j) {
      int row = rt * 128 + wave * 32 + a * 16 + fk * 4 + j;
      #pragma unroll
      for (int b = 0; b < 4; ++b)
        dst[(size_t)row * 64 + b * 16 + fr] = acc[a][b][j];
    }
}

// ---------------- 3b) reduce partials + bias -> q,k ----------------
__global__ void k_qk_reduce(const float* __restrict__ part,
                            const float* __restrict__ b1, const float* __restrict__ b2,
                            float* __restrict__ q, float* __restrict__ kq) {
  int idx = blockIdx.x * 256 + threadIdx.x;   // 0 .. 524287
  int which = idx >> 18;
  int rn = idx & 262143;
  int n = rn & 63;
  float s = which ? b2[n] : b1[n];
  const float* p = part + (size_t)which * 8 * 262144 + rn;
  #pragma unroll
  for (int i = 0; i < 8; ++i) s += p[(size_t)i * 262144];
  (which ? kq : q)[rn] = s;
}

// ---------------- 4) scores + act(bf16) + rowsum (one block per batch) ----------------
__global__ void k_scores(const float* __restrict__ q, const float* __restrict__ kbuf,
                         const float* __restrict__ aw,
                         u16* __restrict__ actb, float* __restrict__ rowsum) {
  __shared__ float qs[128][66], ks2[128][66];
  __shared__ float sc[128][129];
  __shared__ float mxh[2][128], smh[2][128], rsh[2][128];
  const int b = blockIdx.x, tid = threadIdx.x;
  #pragma unroll
  for (int i = 0; i < 8; ++i) {               // stage q,k : 128x64 each
    int f = tid + i * 256; int r = f >> 4, c = (f & 15) * 4;
    f32x4 vq = *(const f32x4*)&q[((size_t)b * 128 + r) * 64 + c];
    qs[r][c] = vq[0]; qs[r][c+1] = vq[1]; qs[r][c+2] = vq[2]; qs[r][c+3] = vq[3];
    f32x4 vk = *(const f32x4*)&kbuf[((size_t)b * 128 + r) * 64 + c];
    ks2[r][c] = vk[0]; ks2[r][c+1] = vk[1]; ks2[r][c+2] = vk[2]; ks2[r][c+3] = vk[3];
  }
  __syncthreads();
  const int tx = tid & 15, ty = tid >> 4;
  float a8[8][8] = {};
  for (int c = 0; c < 64; ++c) {
    float qv[8], kv[8];
    #pragma unroll
    for (int i = 0; i < 8; ++i) qv[i] = qs[ty * 8 + i][c];
    #pragma unroll
    for (int j = 0; j < 8; ++j) kv[j] = ks2[tx + j * 16][c];
    #pragma unroll
    for (int i = 0; i < 8; ++i)
      #pragma unroll
      for (int j = 0; j < 8; ++j)
        a8[i][j] += qv[i] * kv[j];
  }
  #pragma unroll
  for (int i = 0; i < 8; ++i)
    #pragma unroll
    for (int j = 0; j < 8; ++j)
      sc[ty * 8 + i][tx + j * 16] = a8[i][j];
  __syncthreads();
  const int sc_ = tid & 127, hh = tid >> 7;   // split each column across 2 threads
  {
    float m = -INFINITY;
    for (int t = hh * 64; t < hh * 64 + 64; ++t) m = fmaxf(m, sc[t][sc_]);
    mxh[hh][sc_] = m;
  }
  __syncthreads();
  {
    float m = fmaxf(mxh[0][sc_], mxh[1][sc_]);
    float ss = 0.f;
    for (int t = hh * 64; t < hh * 64 + 64; ++t) ss += __expf(sc[t][sc_] - m);
    smh[hh][sc_] = ss;
  }
  __syncthreads();
  const float w0 = aw[0], w1a = aw[1], w2a = aw[2];
  #pragma unroll
  for (int i = 0; i < 8; ++i)
    #pragma unroll
    for (int j = 0; j < 8; ++j) {
      int t = ty * 8 + i, s = tx + j * 16;
      float m = fmaxf(mxh[0][s], mxh[1][s]);
      float dn = smh[0][s] + smh[1][s];
      float v = sc[t][s];
      float av = w0 * fmaxf(v, 0.f)
               + w1a * (1.f / (1.f + __expf(-v)))
               + w2a * (__expf(v - m) / dn);
      actb[((size_t)b * 128 + t) * 128 + s] = f2bf(av);
      sc[t][s] = av;                          // own slot; re-read after barrier
    }
  __syncthreads();
  {
    int t = tid & 127;
    float s_ = 0.f;
    for (int s = hh * 64; s < hh * 64 + 64; ++s) s_ += sc[t][s];
    rsh[hh][t] = s_;
  }
  __syncthreads();
  if (tid < 128) rowsum[b * 128 + tid] = rsh[0][tid] + rsh[1][tid];
}

// ---------------- 5) y = act(bf16) @ x1tb^T via MFMA ----------------
__global__ __launch_bounds__(256) void k_y(const u16* __restrict__ actb,
                                           const u16* __restrict__ x1tb,
                                           u16* __restrict__ yb) {
  __shared__ __align__(16) u16 Ab[128 * 128];  // 32KB, 16-chunk rows, XOR(r&15)
  __shared__ __align__(16) u16 Bs[128 * 128];  // 32KB
  const int bb = blockIdx.y, c0 = blockIdx.x * 128, tid = threadIdx.x;
  const int wave = tid >> 6, lane = tid & 63;
  const int wm = wave >> 1, wn = wave & 1;
  const int fr = lane & 15, fk = lane >> 4;
  #pragma unroll
  for (int i = 0; i < 8; ++i) {
    int ci = tid + i * 256; int r = ci >> 4, c16 = ci & 15;
    u16x8 va = *(const u16x8*)&actb[((size_t)bb * 128 + r) * 128 + c16 * 8];
    *(u16x8*)((char*)Ab + r * 256 + ((c16 ^ (r & 15)) * 16)) = va;
    u16x8 vb = *(const u16x8*)&x1tb[((size_t)bb * CIN + c0 + r) * 128 + c16 * 8];
    *(u16x8*)((char*)Bs + r * 256 + ((c16 ^ (r & 15)) * 16)) = vb;
  }
  __syncthreads();
  f32x4 acc[4][4];
  #pragma unroll
  for (int a = 0; a < 4; ++a)
    #pragma unroll
    for (int b = 0; b < 4; ++b) acc[a][b] = (f32x4){0.f, 0.f, 0.f, 0.f};
  #pragma unroll
  for (int ks = 0; ks < 4; ++ks) {
    bf16x8 af[4], bf[4];
    #pragma unroll
    for (int a = 0; a < 4; ++a) {
      int ra = wm * 64 + a * 16 + fr;
      af[a] = *(const bf16x8*)((const char*)Ab + ra * 256 + (((ks * 4 + fk) ^ (ra & 15)) * 16));
    }
    #pragma unroll
    for (int b = 0; b < 4; ++b) {
      int rb = wn * 64 + b * 16 + fr;
      bf[b] = *(const bf16x8*)((const char*)Bs + rb * 256 + (((ks * 4 + fk) ^ (rb & 15)) * 16));
    }
    #pragma unroll
    for (int a = 0; a < 4; ++a)
      #pragma unroll
      for (int b = 0; b < 4; ++b)
        acc[a][b] = __builtin_amdgcn_mfma_f32_16x16x32_bf16(af[a], bf[b], acc[a][b], 0, 0, 0);
  }
  #pragma unroll
  for (int a = 0; a < 4; ++a)
    #pragma unroll
    for (int j = 0; j < 4; ++j) {
      int t = wm * 64 + a * 16 + fk * 4 + j;
      #pragma unroll
      for (int b = 0; b < 4; ++b) {
        int c = c0 + wn * 64 + b * 16 + fr;
        yb[((size_t)bb * 128 + t) * CIN + c] = f2bf(acc[a][b][j]);
      }
    }
}

// ---------------- 6) out = y(bf16) @ wg^T(bf16) + rowsum ⊗ bg ----------------
// m97 structure + bijective XCD swizzle (nwg=1024, 1024%8==0 -> m157 form safe)
#define BM 128
#define BN 128
#define BK 64
__global__ __launch_bounds__(256) void k_gemm(
    const u16* __restrict__ A, const u16* __restrict__ Bw,
    const float* __restrict__ rowsum, const float* __restrict__ bg,
    float* __restrict__ C) {
  __shared__ __align__(16) u16 As[BM * BK];   // 16 KB
  __shared__ __align__(16) u16 Bs[BN * BK];   // 16 KB
  const int tid = threadIdx.x;
  const int wave = tid >> 6, lane = tid & 63;
  const int orig = blockIdx.y * 32 + blockIdx.x;
  const int wgid = (orig & 7) * 128 + (orig >> 3);   // XCD-aware, bijective
  const int row0 = (wgid >> 5) * BM, col0 = (wgid & 31) * BN;
  const int wm = wave >> 1, wn = wave & 1;
  const int fr = lane & 15, fk = lane >> 4;

  const int srow = tid >> 3;
  const int schunk = (tid & 7) ^ (srow & 7);
  const u16* Abase = A + (size_t)(row0 + srow) * CIN + schunk * 8;
  const u16* Bbase = Bw + (size_t)(col0 + srow) * CIN + schunk * 8;

  f32x4 acc[4][4];
  #pragma unroll
  for (int a = 0; a < 4; ++a)
    #pragma unroll
    for (int b = 0; b < 4; ++b) acc[a][b] = (f32x4){0.f, 0.f, 0.f, 0.f};

  for (int kt = 0; kt < CIN; kt += BK) {
    #pragma unroll
    for (int i = 0; i < 4; ++i) {
      gload_lds16(Abase + (size_t)i * 32 * CIN + kt, (char*)As + i * 4096 + wave * 1024);
      gload_lds16(Bbase + (size_t)i * 32 * CIN + kt, (char*)Bs + i * 4096 + wave * 1024);
    }
    __syncthreads();
    #pragma unroll
    for (int ks = 0; ks < 2; ++ks) {
      bf16x8 af[4], bf[4];
      #pragma unroll
      for (int a = 0; a < 4; ++a) {
        int r = wm * 64 + a * 16 + fr;
        int ch = (ks * 4 + fk) ^ (r & 7);
        af[a] = *(const bf16x8*)((const char*)As + r * 128 + ch * 16);
      }
      #pragma unroll
      for (int b = 0; b < 4; ++b) {
        int r = wn * 64 + b * 16 + fr;
        int ch = (ks * 4 + fk) ^ (r & 7);
        bf[b] = *(const bf16x8*)((const char*)Bs + r * 128 + ch * 16);
      }
      #pragma unroll
      for (int a = 0; a < 4; ++a)
        #pragma unroll
        for (int b = 0; b < 4; ++b)
          acc[a][b] = __builtin_amdgcn_mfma_f32_16x16x32_bf16(af[a], bf[b], acc[a][b], 0, 0, 0);
    }
    __syncthreads();
  }

  float bgv[4];
  #pragma unroll
  for (int b = 0; b < 4; ++b) bgv[b] = bg[col0 + wn * 64 + b * 16 + fr];
  #pragma unroll
  for (int a = 0; a < 4; ++a)
    #pragma unroll
    for (int j = 0; j < 4; ++j) {
      int r = row0 + wm * 64 + a * 16 + fk * 4 + j;
      float rs = rowsum[r];
      #pragma unroll
      for (int b = 0; b < 4; ++b) {
        int c = col0 + wn * 64 + b * 16 + fr;
        C[(size_t)r * GOUT + c] = acc[a][b][j] + rs * bgv[b];
      }
    }
}

extern "C" void kernel_launch(void* const* d_in, const int* in_sizes, int n_in,
                              void* d_out, int out_size, void* d_ws, size_t ws_size,
                              hipStream_t stream) {
  const float* x1 = (const float*)d_in[0];
  const float* x2 = (const float*)d_in[1];
  const float* aw = (const float*)d_in[2];
  const float* w1 = (const float*)d_in[3];
  const float* b1 = (const float*)d_in[4];
  const float* w2 = (const float*)d_in[5];
  const float* b2 = (const float*)d_in[6];
  const float* wg = (const float*)d_in[7];
  const float* bg = (const float*)d_in[8];
  float* out = (float*)d_out;
  char* ws = (char*)d_ws;

  // workspace map (100 MiB). part (16 MiB) aliases yb: dead before k_y writes.
  float* q    = (float*)(ws);                      // 1 MiB
  float* kq   = (float*)(ws + 1048576);            // 1 MiB
  u16*   actb = (u16*)(ws + 2097152);              // 1 MiB
  float* rsum = (float*)(ws + 3145728);            // 16 KiB
  u16*   wgb  = (u16*)(ws + 4194304);              // 32 MiB
  u16*   x1tb = (u16*)(ws + 37748736);             // 32 MiB
  u16*   yb   = (u16*)(ws + 71303168);             // 32 MiB -> end 100 MiB
  float* part = (float*)(ws + 71303168);           // 16 MiB (aliases yb)

  hipLaunchKernelGGL(k_conv_wg,    dim3(8192),      dim3(256), 0, stream, wg, wgb);
  hipLaunchKernelGGL(k_x1t,        dim3(32, 32),    dim3(256), 0, stream, x1, x1tb);
  hipLaunchKernelGGL(k_qk_partial, dim3(32, 8, 2),  dim3(256), 0, stream,
                     x1, x2, w1, w2, part);
  hipLaunchKernelGGL(k_qk_reduce,  dim3(2048),      dim3(256), 0, stream, part, b1, b2, q, kq);
  hipLaunchKernelGGL(k_scores,     dim3(32),        dim3(256), 0, stream, q, kq, aw, actb, rsum);
  hipLaunchKernelGGL(k_y,          dim3(32, 32),    dim3(256), 0, stream, actb, x1tb, yb);
  hipLaunchKernelGGL(k_gemm,       dim3(32, 32),    dim3(256), 0, stream, yb, wgb, rsum, bg, out);
}

// Round 5
// 395.971 us; speedup vs baseline: 1.3338x; 1.1356x over previous
//
#include <hip/hip_runtime.h>
#include <math.h>

// Problem constants
#define B_   32
#define T_   128
#define CIN  4096
#define NF   64
#define GOUT 4096

typedef unsigned short u16;
typedef __attribute__((ext_vector_type(4))) float  f32x4;
typedef __attribute__((ext_vector_type(8))) __bf16 bf16x8;
typedef __attribute__((ext_vector_type(8))) u16    u16x8;

__device__ __forceinline__ u16 f2bf(float f) {   // RNE f32->bf16
  union { float f; unsigned u; } v; v.f = f;
  unsigned r = v.u + 0x7fffu + ((v.u >> 16) & 1u);
  return (u16)(r >> 16);
}

__device__ __forceinline__ void gload_lds16(const void* g, void* l) {
  __builtin_amdgcn_global_load_lds(
      (const __attribute__((address_space(1))) void*)g,
      (__attribute__((address_space(3))) void*)l, 16, 0, 0);
}

template<int N> __device__ __forceinline__ void waitvm() {
  if constexpr (N == 8) asm volatile("s_waitcnt vmcnt(8)" ::: "memory");
  else if constexpr (N == 4) asm volatile("s_waitcnt vmcnt(4)" ::: "memory");
  else asm volatile("s_waitcnt vmcnt(0)" ::: "memory");
}

// ---------------- 1) wg f32 -> bf16 ----------------
__global__ void k_conv_wg(const float* __restrict__ wg, u16* __restrict__ wgb) {
  size_t i = ((size_t)blockIdx.x * 256 + threadIdx.x) * 8;
  f32x4 a = *(const f32x4*)&wg[i];
  f32x4 b = *(const f32x4*)&wg[i + 4];
  u16x8 o;
  o[0]=f2bf(a[0]); o[1]=f2bf(a[1]); o[2]=f2bf(a[2]); o[3]=f2bf(a[3]);
  o[4]=f2bf(b[0]); o[5]=f2bf(b[1]); o[6]=f2bf(b[2]); o[7]=f2bf(b[3]);
  *(u16x8*)&wgb[i] = o;
}

// ---------------- 2) x1 -> x1tb : per-batch transpose + bf16 ----------------
__global__ __launch_bounds__(256) void k_x1t(const float* __restrict__ x1,
                                             u16* __restrict__ x1tb) {
  __shared__ float tile[128][132];
  const int b = blockIdx.y, c0 = blockIdx.x * 128, tid = threadIdx.x;
  #pragma unroll
  for (int i = 0; i < 16; ++i) {
    int f = tid + i * 256; int s = f >> 5, c4 = (f & 31) * 4;
    f32x4 v = *(const f32x4*)&x1[((size_t)b * 128 + s) * CIN + c0 + c4];
    tile[s][c4] = v[0]; tile[s][c4+1] = v[1]; tile[s][c4+2] = v[2]; tile[s][c4+3] = v[3];
  }
  __syncthreads();
  const int c = tid >> 1, sh = (tid & 1) * 64;
  #pragma unroll
  for (int i = 0; i < 8; ++i) {
    u16x8 o;
    #pragma unroll
    for (int j = 0; j < 8; ++j) o[j] = f2bf(tile[sh + i * 8 + j][c]);
    *(u16x8*)&x1tb[((size_t)b * CIN + c0 + c) * 128 + sh + i * 8] = o;
  }
}

// ---------------- 3a) q/k partials via MFMA, K-split x8 ----------------
__global__ __launch_bounds__(256) void k_qk_partial(
    const float* __restrict__ x1, const float* __restrict__ x2,
    const float* __restrict__ w1, const float* __restrict__ w2,
    float* __restrict__ part) {
  const int rt = blockIdx.x, ksp = blockIdx.y, which = blockIdx.z;
  const float* __restrict__ X = which ? x2 : x1;
  const float* __restrict__ W = which ? w2 : w1;
  __shared__ __align__(16) u16 Xs[128 * 64];
  __shared__ __align__(16) u16 Ws[64 * 64];
  const int tid = threadIdx.x;
  const int wave = tid >> 6, lane = tid & 63;
  const int fr = lane & 15, fk = lane >> 4;
  f32x4 acc[2][4];
  #pragma unroll
  for (int a = 0; a < 2; ++a)
    #pragma unroll
    for (int b = 0; b < 4; ++b) acc[a][b] = (f32x4){0.f, 0.f, 0.f, 0.f};

  for (int step = 0; step < 8; ++step) {
    const int kbase = ksp * 512 + step * 64;
    __syncthreads();
    #pragma unroll
    for (int i = 0; i < 4; ++i) {
      int ci = tid + i * 256; int r = ci >> 3, c8 = ci & 7;
      const float* s = &X[((size_t)rt * 128 + r) * CIN + kbase + c8 * 8];
      f32x4 va = *(const f32x4*)s, vb = *(const f32x4*)(s + 4);
      bf16x8 o;
      o[0]=(__bf16)va[0]; o[1]=(__bf16)va[1]; o[2]=(__bf16)va[2]; o[3]=(__bf16)va[3];
      o[4]=(__bf16)vb[0]; o[5]=(__bf16)vb[1]; o[6]=(__bf16)vb[2]; o[7]=(__bf16)vb[3];
      *(bf16x8*)((char*)Xs + r * 128 + ((c8 ^ (r & 7)) * 16)) = o;
    }
    #pragma unroll
    for (int i = 0; i < 2; ++i) {
      int ci = tid + i * 256; int r = ci >> 3, c8 = ci & 7;
      const float* s = &W[(size_t)r * CIN + kbase + c8 * 8];
      f32x4 va = *(const f32x4*)s, vb = *(const f32x4*)(s + 4);
      bf16x8 o;
      o[0]=(__bf16)va[0]; o[1]=(__bf16)va[1]; o[2]=(__bf16)va[2]; o[3]=(__bf16)va[3];
      o[4]=(__bf16)vb[0]; o[5]=(__bf16)vb[1]; o[6]=(__bf16)vb[2]; o[7]=(__bf16)vb[3];
      *(bf16x8*)((char*)Ws + r * 128 + ((c8 ^ (r & 7)) * 16)) = o;
    }
    __syncthreads();
    #pragma unroll
    for (int ks = 0; ks < 2; ++ks) {
      bf16x8 af[2], bf[4];
      #pragma unroll
      for (int a = 0; a < 2; ++a) {
        int ra = wave * 32 + a * 16 + fr;
        af[a] = *(const bf16x8*)((const char*)Xs + ra * 128 + (((ks * 4 + fk) ^ (ra & 7)) * 16));
      }
      #pragma unroll
      for (int b = 0; b < 4; ++b) {
        int rb = b * 16 + fr;
        bf[b] = *(const bf16x8*)((const char*)Ws + rb * 128 + (((ks * 4 + fk) ^ (rb & 7)) * 16));
      }
      #pragma unroll
      for (int a = 0; a < 2; ++a)
        #pragma unroll
        for (int b = 0; b < 4; ++b)
          acc[a][b] = __builtin_amdgcn_mfma_f32_16x16x32_bf16(af[a], bf[b], acc[a][b], 0, 0, 0);
    }
  }
  float* dst = part + ((size_t)(which * 8 + ksp)) * 262144;
  #pragma unroll
  for (int a = 0; a < 2; ++a)
    #pragma unroll
    for (int j = 0; j < 4; ++j) {
      int row = rt * 128 + wave * 32 + a * 16 + fk * 4 + j;
      #pragma unroll
      for (int b = 0; b < 4; ++b)
        dst[(size_t)row * 64 + b * 16 + fr] = acc[a][b][j];
    }
}

// ---------------- 3b) reduce partials + bias -> q,k ----------------
__global__ void k_qk_reduce(const float* __restrict__ part,
                            const float* __restrict__ b1, const float* __restrict__ b2,
                            float* __restrict__ q, float* __restrict__ kq) {
  int idx = blockIdx.x * 256 + threadIdx.x;
  int which = idx >> 18;
  int rn = idx & 262143;
  int n = rn & 63;
  float s = which ? b2[n] : b1[n];
  const float* p = part + (size_t)which * 8 * 262144 + rn;
  #pragma unroll
  for (int i = 0; i < 8; ++i) s += p[(size_t)i * 262144];
  (which ? kq : q)[rn] = s;
}

// ---------------- 4) scores + act(bf16) + rowsum partials ----------------
// grid (32 batches, 4 s-tiles), 256 thr. Block covers all 128 t x 32 s-cols,
// so the column softmax (axis=1 == over t) is fully block-local.
__global__ __launch_bounds__(256) void k_scores(
    const float* __restrict__ q, const float* __restrict__ kbuf,
    const float* __restrict__ aw, u16* __restrict__ actb,
    float* __restrict__ rsum_part) {
  __shared__ float qs[128][68];
  __shared__ float ksm[32][76];
  __shared__ float lred[16][33];
  __shared__ float colm[32], colsum[32];
  __shared__ float rsl[128][17];
  const int b = blockIdx.x, sblk = blockIdx.y, s0 = sblk * 32, tid = threadIdx.x;
  const int tx = tid & 15, ty = tid >> 4;
  #pragma unroll
  for (int i = 0; i < 8; ++i) {
    int f = tid + i * 256; int r = f >> 4, c4 = (f & 15) * 4;
    *(f32x4*)&qs[r][c4] = *(const f32x4*)&q[((size_t)b * 128 + r) * 64 + c4];
  }
  #pragma unroll
  for (int i = 0; i < 2; ++i) {
    int f = tid + i * 256; int r = f >> 4, c4 = (f & 15) * 4;
    *(f32x4*)&ksm[r][c4] = *(const f32x4*)&kbuf[((size_t)b * 128 + s0 + r) * 64 + c4];
  }
  __syncthreads();
  float a8[8][2] = {};
  for (int c4 = 0; c4 < 64; c4 += 4) {
    f32x4 kv0 = *(const f32x4*)&ksm[tx * 2][c4];
    f32x4 kv1 = *(const f32x4*)&ksm[tx * 2 + 1][c4];
    #pragma unroll
    for (int i = 0; i < 8; ++i) {
      f32x4 qv = *(const f32x4*)&qs[ty * 8 + i][c4];
      a8[i][0] += qv[0]*kv0[0] + qv[1]*kv0[1] + qv[2]*kv0[2] + qv[3]*kv0[3];
      a8[i][1] += qv[0]*kv1[0] + qv[1]*kv1[1] + qv[2]*kv1[2] + qv[3]*kv1[3];
    }
  }
  {  // column max
    float m0 = a8[0][0], m1 = a8[0][1];
    #pragma unroll
    for (int i = 1; i < 8; ++i) { m0 = fmaxf(m0, a8[i][0]); m1 = fmaxf(m1, a8[i][1]); }
    lred[ty][tx * 2] = m0; lred[ty][tx * 2 + 1] = m1;
  }
  __syncthreads();
  if (tid < 32) {
    float m = lred[0][tid];
    #pragma unroll
    for (int t = 1; t < 16; ++t) m = fmaxf(m, lred[t][tid]);
    colm[tid] = m;
  }
  __syncthreads();
  const float m0 = colm[tx * 2], m1 = colm[tx * 2 + 1];
  {  // column exp-sum
    float e0 = 0.f, e1 = 0.f;
    #pragma unroll
    for (int i = 0; i < 8; ++i) { e0 += __expf(a8[i][0] - m0); e1 += __expf(a8[i][1] - m1); }
    lred[ty][tx * 2] = e0; lred[ty][tx * 2 + 1] = e1;
  }
  __syncthreads();
  if (tid < 32) {
    float s = 0.f;
    #pragma unroll
    for (int t = 0; t < 16; ++t) s += lred[t][tid];
    colsum[tid] = s;
  }
  __syncthreads();
  const float d0 = colsum[tx * 2], d1 = colsum[tx * 2 + 1];
  const float w0 = aw[0], w1a = aw[1], w2a = aw[2];
  #pragma unroll
  for (int i = 0; i < 8; ++i) {
    int t = ty * 8 + i;
    float v0 = a8[i][0], v1 = a8[i][1];
    float av0 = w0 * fmaxf(v0, 0.f) + w1a * (1.f / (1.f + __expf(-v0)))
              + w2a * (__expf(v0 - m0) / d0);
    float av1 = w0 * fmaxf(v1, 0.f) + w1a * (1.f / (1.f + __expf(-v1)))
              + w2a * (__expf(v1 - m1) / d1);
    unsigned pk = (unsigned)f2bf(av0) | ((unsigned)f2bf(av1) << 16);
    *(unsigned*)&actb[((size_t)b * 128 + t) * 128 + s0 + tx * 2] = pk;
    rsl[t][tx] = av0 + av1;
  }
  __syncthreads();
  if (tid < 128) {
    float s = 0.f;
    #pragma unroll
    for (int x = 0; x < 16; ++x) s += rsl[tid][x];
    rsum_part[sblk * 4096 + b * 128 + tid] = s;
  }
}

// ---------------- 5) y = act(bf16) @ x1tb^T via MFMA ----------------
__global__ __launch_bounds__(256) void k_y(const u16* __restrict__ actb,
                                           const u16* __restrict__ x1tb,
                                           u16* __restrict__ yb) {
  __shared__ __align__(16) u16 Ab[128 * 128];
  __shared__ __align__(16) u16 Bs[128 * 128];
  const int bb = blockIdx.y, c0 = blockIdx.x * 128, tid = threadIdx.x;
  const int wave = tid >> 6, lane = tid & 63;
  const int wm = wave >> 1, wn = wave & 1;
  const int fr = lane & 15, fk = lane >> 4;
  #pragma unroll
  for (int i = 0; i < 8; ++i) {
    int ci = tid + i * 256; int r = ci >> 4, c16 = ci & 15;
    u16x8 va = *(const u16x8*)&actb[((size_t)bb * 128 + r) * 128 + c16 * 8];
    *(u16x8*)((char*)Ab + r * 256 + ((c16 ^ (r & 15)) * 16)) = va;
    u16x8 vb = *(const u16x8*)&x1tb[((size_t)bb * CIN + c0 + r) * 128 + c16 * 8];
    *(u16x8*)((char*)Bs + r * 256 + ((c16 ^ (r & 15)) * 16)) = vb;
  }
  __syncthreads();
  f32x4 acc[4][4];
  #pragma unroll
  for (int a = 0; a < 4; ++a)
    #pragma unroll
    for (int b = 0; b < 4; ++b) acc[a][b] = (f32x4){0.f, 0.f, 0.f, 0.f};
  #pragma unroll
  for (int ks = 0; ks < 4; ++ks) {
    bf16x8 af[4], bf[4];
    #pragma unroll
    for (int a = 0; a < 4; ++a) {
      int ra = wm * 64 + a * 16 + fr;
      af[a] = *(const bf16x8*)((const char*)Ab + ra * 256 + (((ks * 4 + fk) ^ (ra & 15)) * 16));
    }
    #pragma unroll
    for (int b = 0; b < 4; ++b) {
      int rb = wn * 64 + b * 16 + fr;
      bf[b] = *(const bf16x8*)((const char*)Bs + rb * 256 + (((ks * 4 + fk) ^ (rb & 15)) * 16));
    }
    #pragma unroll
    for (int a = 0; a < 4; ++a)
      #pragma unroll
      for (int b = 0; b < 4; ++b)
        acc[a][b] = __builtin_amdgcn_mfma_f32_16x16x32_bf16(af[a], bf[b], acc[a][b], 0, 0, 0);
  }
  #pragma unroll
  for (int a = 0; a < 4; ++a)
    #pragma unroll
    for (int j = 0; j < 4; ++j) {
      int t = wm * 64 + a * 16 + fk * 4 + j;
      #pragma unroll
      for (int b = 0; b < 4; ++b) {
        int c = c0 + wn * 64 + b * 16 + fr;
        yb[((size_t)bb * 128 + t) * CIN + c] = f2bf(acc[a][b][j]);
      }
    }
}

// ---------------- 6) out = y @ wg^T + rowsum ⊗ bg : 256² 8-phase ----------------
// 512 thr (8 waves 2Mx4N), K in 128 sub-tiles of 32; 4-slot LDS ring (128 KB).
// Counted vmcnt(8) (2 loads/unit x 4 units in flight) — never drains in-loop.
// LDS layout per sub-tile: [128 pairs][8 slots x 16B]; slot s at pair p holds
// global chunk c = s ^ (p&7), c = (row-of-pair h = c>>2, K-group k4 = c&3).
// Source pre-swizzle + read swizzle = same involution (rule 21).
#define NT 128
__global__ __launch_bounds__(512, 2) void k_gemm8(
    const u16* __restrict__ A, const u16* __restrict__ Bw,
    const float* __restrict__ rsum_part, const float* __restrict__ bg,
    float* __restrict__ C) {
  extern __shared__ __align__(16) char smem[];   // 128 KB: A ring 64K | B ring 64K
  const int tid = threadIdx.x;
  const int wave = tid >> 6, lane = tid & 63;
  const int fr = lane & 15, fk = lane >> 4;
  const int wm = wave >> 2, wn = wave & 3;
  // 2-D XCD swizzle: XCD x owns a 4x8 region of the 16x16 tile grid
  const int bid = blockIdx.x;
  const int xcd = bid & 7, idx = bid >> 3;
  const int rowT = (xcd >> 1) * 4 + (idx >> 3);
  const int colT = (xcd & 1) * 8 + (idx & 7);
  const int row0 = rowT * 256, col0 = colT * 256;

#define STAGE_UNIT(G, rowstart, isB, u_) do {                                  \
    char* db_ = smem + ((isB) ? 65536 : 0) + ((u_) & 3) * 16384 + wave * 1024; \
    _Pragma("unroll")                                                          \
    for (int l_ = 0; l_ < 2; ++l_) {                                           \
      int ci_ = l_ * 512 + tid; int p_ = ci_ >> 3, sl_ = ci_ & 7;              \
      int c_ = sl_ ^ (p_ & 7);                                                 \
      const u16* src_ = (G) + (size_t)((rowstart) + 2 * p_ + (c_ >> 2)) * CIN  \
                        + (u_) * 32 + (c_ & 3) * 8;                            \
      gload_lds16(src_, db_ + l_ * 8192);                                      \
    }                                                                          \
  } while (0)

#define LDA_FRAG(dst, q_, rowa) do {                                           \
    int pA_ = (rowa) >> 1, hA_ = (rowa) & 1;                                   \
    dst = *(const bf16x8*)(smem + (q_) * 16384 + pA_ * 128                     \
                           + (((hA_ * 4 + fk) ^ (pA_ & 7)) * 16)); } while (0)
#define LDB_FRAG(dst, q_, rowb) do {                                           \
    int pB_ = (rowb) >> 1, hB_ = (rowb) & 1;                                   \
    dst = *(const bf16x8*)(smem + 65536 + (q_) * 16384 + pB_ * 128             \
                           + (((hB_ * 4 + fk) ^ (pB_ & 7)) * 16)); } while (0)

  f32x4 acc[8][4];
  #pragma unroll
  for (int m = 0; m < 8; ++m)
    #pragma unroll
    for (int n = 0; n < 4; ++n) acc[m][n] = (f32x4){0.f, 0.f, 0.f, 0.f};

  // prologue: stage sub-tiles 0,1,2 (A+B each = 12 loads); need sub 0 landed
  STAGE_UNIT(A, row0, 0, 0); STAGE_UNIT(Bw, col0, 1, 0);
  STAGE_UNIT(A, row0, 0, 1); STAGE_UNIT(Bw, col0, 1, 1);
  STAGE_UNIT(A, row0, 0, 2); STAGE_UNIT(Bw, col0, 1, 2);
  waitvm<8>();
  __builtin_amdgcn_s_barrier();
  __builtin_amdgcn_sched_barrier(0);

#define SUBTILE(u_, VN_, DOSTG_) do {                                          \
    const int q_ = (u_) & 3;                                                   \
    bf16x8 afr[4], bfr[4];                                                     \
    _Pragma("unroll")                                                          \
    for (int n = 0; n < 4; ++n) LDB_FRAG(bfr[n], q_, wn * 64 + n * 16 + fr);   \
    _Pragma("unroll")                                                          \
    for (int m = 0; m < 4; ++m) LDA_FRAG(afr[m], q_, wm * 128 + m * 16 + fr);  \
    if (DOSTG_) STAGE_UNIT(A, row0, 0, (u_) + 3);                              \
    __builtin_amdgcn_s_barrier();                                              \
    __builtin_amdgcn_sched_barrier(0);                                         \
    __builtin_amdgcn_s_setprio(1);                                             \
    _Pragma("unroll")                                                          \
    for (int m = 0; m < 4; ++m)                                                \
      _Pragma("unroll")                                                        \
      for (int n = 0; n < 4; ++n)                                              \
        acc[m][n] = __builtin_amdgcn_mfma_f32_16x16x32_bf16(afr[m], bfr[n],    \
                                                            acc[m][n], 0, 0, 0); \
    __builtin_amdgcn_s_setprio(0);                                             \
    __builtin_amdgcn_s_barrier();                                              \
    __builtin_amdgcn_sched_barrier(0);                                         \
    _Pragma("unroll")                                                          \
    for (int m = 0; m < 4; ++m)                                                \
      LDA_FRAG(afr[m], q_, wm * 128 + (m + 4) * 16 + fr);                      \
    if (DOSTG_) STAGE_UNIT(Bw, col0, 1, (u_) + 3);                             \
    waitvm<VN_>();                                                             \
    __builtin_amdgcn_s_barrier();                                              \
    __builtin_amdgcn_sched_barrier(0);                                         \
    __builtin_amdgcn_s_setprio(1);                                             \
    _Pragma("unroll")                                                          \
    for (int m = 0; m < 4; ++m)                                                \
      _Pragma("unroll")                                                        \
      for (int n = 0; n < 4; ++n)                                              \
        acc[m + 4][n] = __builtin_amdgcn_mfma_f32_16x16x32_bf16(afr[m], bfr[n], \
                                                            acc[m + 4][n], 0, 0, 0); \
    __builtin_amdgcn_s_setprio(0);                                             \
    __builtin_amdgcn_s_barrier();                                              \
    __builtin_amdgcn_sched_barrier(0);                                         \
  } while (0)

  #pragma unroll 1
  for (int u = 0; u < 125; ++u) SUBTILE(u, 8, 1);
  SUBTILE(125, 4, 0);
  SUBTILE(126, 0, 0);
  SUBTILE(127, 0, 0);

  // epilogue
  float bgv[4];
  #pragma unroll
  for (int n = 0; n < 4; ++n) bgv[n] = bg[col0 + wn * 64 + n * 16 + fr];
  #pragma unroll
  for (int m = 0; m < 8; ++m)
    #pragma unroll
    for (int j = 0; j < 4; ++j) {
      int r = row0 + wm * 128 + m * 16 + fk * 4 + j;
      float rs = rsum_part[r] + rsum_part[4096 + r]
               + rsum_part[8192 + r] + rsum_part[12288 + r];
      #pragma unroll
      for (int n = 0; n < 4; ++n) {
        int c = col0 + wn * 64 + n * 16 + fr;
        C[(size_t)r * GOUT + c] = acc[m][n][j] + rs * bgv[n];
      }
    }
#undef SUBTILE
#undef STAGE_UNIT
#undef LDA_FRAG
#undef LDB_FRAG
}

extern "C" void kernel_launch(void* const* d_in, const int* in_sizes, int n_in,
                              void* d_out, int out_size, void* d_ws, size_t ws_size,
                              hipStream_t stream) {
  const float* x1 = (const float*)d_in[0];
  const float* x2 = (const float*)d_in[1];
  const float* aw = (const float*)d_in[2];
  const float* w1 = (const float*)d_in[3];
  const float* b1 = (const float*)d_in[4];
  const float* w2 = (const float*)d_in[5];
  const float* b2 = (const float*)d_in[6];
  const float* wg = (const float*)d_in[7];
  const float* bg = (const float*)d_in[8];
  float* out = (float*)d_out;
  char* ws = (char*)d_ws;

  // workspace map (100 MiB). part (16 MiB) aliases yb: dead before k_y writes.
  float* q    = (float*)(ws);                      // 1 MiB
  float* kq   = (float*)(ws + 1048576);            // 1 MiB
  u16*   actb = (u16*)(ws + 2097152);              // 1 MiB
  float* rsum = (float*)(ws + 3145728);            // 64 KiB (4 partials x 4096)
  u16*   wgb  = (u16*)(ws + 4194304);              // 32 MiB
  u16*   x1tb = (u16*)(ws + 37748736);             // 32 MiB
  u16*   yb   = (u16*)(ws + 71303168);             // 32 MiB -> end 100 MiB
  float* part = (float*)(ws + 71303168);           // 16 MiB (aliases yb)

  hipFuncSetAttribute((const void*)k_gemm8,
                      hipFuncAttributeMaxDynamicSharedMemorySize, 131072);

  hipLaunchKernelGGL(k_conv_wg,    dim3(8192),      dim3(256), 0, stream, wg, wgb);
  hipLaunchKernelGGL(k_x1t,        dim3(32, 32),    dim3(256), 0, stream, x1, x1tb);
  hipLaunchKernelGGL(k_qk_partial, dim3(32, 8, 2),  dim3(256), 0, stream,
                     x1, x2, w1, w2, part);
  hipLaunchKernelGGL(k_qk_reduce,  dim3(2048),      dim3(256), 0, stream, part, b1, b2, q, kq);
  hipLaunchKernelGGL(k_scores,     dim3(32, 4),     dim3(256), 0, stream, q, kq, aw, actb, rsum);
  hipLaunchKernelGGL(k_y,          dim3(32, 32),    dim3(256), 0, stream, actb, x1tb, yb);
  hipLaunchKernelGGL(k_gemm8,      dim3(256),       dim3(512), 131072, stream,
                     yb, wgb, rsum, bg, out);
}